// Round 1
// baseline (266.804 us; speedup 1.0000x reference)
//
#include <hip/hip_runtime.h>
#include <stdint.h>

// ---------------------------------------------------------------------------
// SparseAttention: B=1 S=4096 D=1024 H=16 HD=64, BLOCK=128 C=32
// Pipeline: cvt_x -> tpose4 (W->bf16 [N][K]) -> gemm_bt(QKV) -> attn -> gemm_bt(out)
// ---------------------------------------------------------------------------

#define S_LEN 4096
#define DMODEL 1024

typedef __bf16 bf16x8 __attribute__((ext_vector_type(8)));
typedef float  f32x4  __attribute__((ext_vector_type(4)));

__device__ __forceinline__ uint16_t f2bf(float f) {
    uint32_t u = __builtin_bit_cast(uint32_t, f);
    u += 0x7fffu + ((u >> 16) & 1u);   // RNE
    return (uint16_t)(u >> 16);
}

__device__ __forceinline__ void gload_lds16(const uint16_t* g, uint16_t* l) {
    __builtin_amdgcn_global_load_lds(
        (const __attribute__((address_space(1))) void*)g,
        (__attribute__((address_space(3))) void*)l, 16, 0, 0);
}

// ---------------- x fp32 -> bf16 -------------------------------------------
__global__ __launch_bounds__(256) void cvt_x_kernel(const float* __restrict__ x,
                                                    uint16_t* __restrict__ xb) {
    int i = (blockIdx.x * 256 + threadIdx.x) * 4;
    const float4 v = *(const float4*)(x + i);
    ushort4 o;
    o.x = f2bf(v.x); o.y = f2bf(v.y); o.z = f2bf(v.z); o.w = f2bf(v.w);
    *(ushort4*)(xb + i) = o;
}

// ---------------- W [K=1024][N=1024] fp32 -> [N][K] bf16 -------------------
__global__ __launch_bounds__(256) void tpose4(const float* __restrict__ Wq,
                                              const float* __restrict__ Wk,
                                              const float* __restrict__ Wv,
                                              const float* __restrict__ Wo,
                                              uint16_t* __restrict__ wqkvt,
                                              uint16_t* __restrict__ wot) {
    __shared__ float tile[64][65];
    const int z = blockIdx.z;
    const float* src = (z == 0) ? Wq : (z == 1) ? Wk : (z == 2) ? Wv : Wo;
    uint16_t* dst = (z < 3) ? (wqkvt + (size_t)z * 1024 * 1024) : wot;
    const int ro = blockIdx.y * 64, co = blockIdx.x * 64;
    const int c = threadIdx.x & 63, r4 = threadIdx.x >> 6;
#pragma unroll
    for (int i = 0; i < 16; i++) {
        int r = i * 4 + r4;
        tile[r][c] = src[(size_t)(ro + r) * 1024 + co + c];
    }
    __syncthreads();
#pragma unroll
    for (int i = 0; i < 16; i++) {
        int cc = i * 4 + r4;
        dst[(size_t)(co + cc) * 1024 + ro + c] = f2bf(tile[c][cc]);
    }
}

// ---------------- GEMM: C[M][N] = A[M][1024] * Bt[N][1024]^T ---------------
// mode 0: N=3072 qkv -> bf16 with bias + q*0.125 ; mode 1: N=1024 -> fp32 + bias
__global__ __launch_bounds__(256) void gemm_bt(const uint16_t* __restrict__ A,
                                               const uint16_t* __restrict__ Bt,
                                               const float* __restrict__ bias0,
                                               const float* __restrict__ bias1,
                                               const float* __restrict__ bias2,
                                               uint16_t* __restrict__ Cb,
                                               float* __restrict__ Cf,
                                               const int mode) {
    __shared__ __attribute__((aligned(16))) uint16_t As[128 * 64];
    __shared__ __attribute__((aligned(16))) uint16_t Bs[128 * 64];
    const int tid = threadIdx.x;
    const int wave = tid >> 6, lane = tid & 63;
    const int quad = lane >> 4, l16 = lane & 15;
    const int row0 = blockIdx.y * 128, col0 = blockIdx.x * 128;
    const int wm = (wave >> 1) * 64, wn = (wave & 1) * 64;
    const int srow = lane >> 3, scol = lane & 7;

    f32x4 acc[4][4];
    const f32x4 z4 = {0.f, 0.f, 0.f, 0.f};
#pragma unroll
    for (int i = 0; i < 4; i++)
#pragma unroll
        for (int j = 0; j < 4; j++) acc[i][j] = z4;

    for (int k0 = 0; k0 < 1024; k0 += 64) {
        __syncthreads();
#pragma unroll
        for (int i = 0; i < 4; i++) {
            int u = wave * 4 + i;
            int row = u * 8 + srow;
            gload_lds16(A  + (size_t)(row0 + row) * 1024 + k0 + scol * 8, As + u * 512);
            gload_lds16(Bt + (size_t)(col0 + row) * 1024 + k0 + scol * 8, Bs + u * 512);
        }
        __syncthreads();
#pragma unroll
        for (int kk = 0; kk < 2; kk++) {
            bf16x8 af[4], bfr[4];
#pragma unroll
            for (int mt = 0; mt < 4; mt++)
                af[mt] = *(const bf16x8*)(As + (wm + mt * 16 + l16) * 64 + kk * 32 + quad * 8);
#pragma unroll
            for (int nt = 0; nt < 4; nt++)
                bfr[nt] = *(const bf16x8*)(Bs + (wn + nt * 16 + l16) * 64 + kk * 32 + quad * 8);
#pragma unroll
            for (int mt = 0; mt < 4; mt++)
#pragma unroll
                for (int nt = 0; nt < 4; nt++)
                    acc[mt][nt] = __builtin_amdgcn_mfma_f32_16x16x32_bf16(
                        af[mt], bfr[nt], acc[mt][nt], 0, 0, 0);
        }
    }

    if (mode == 0) {
#pragma unroll
        for (int nt = 0; nt < 4; nt++) {
            int n = col0 + wn + nt * 16 + l16;
            int which = n >> 10, c = n & 1023;
            const float* bp = (which == 0) ? bias0 : (which == 1 ? bias1 : bias2);
            float bi = bp[c];
            float scv = (which == 0) ? 0.125f : 1.0f;
            uint16_t* op = Cb + (size_t)which * S_LEN * 1024 + c;
#pragma unroll
            for (int mt = 0; mt < 4; mt++) {
                int row = row0 + wm + mt * 16 + quad * 4;
#pragma unroll
                for (int r = 0; r < 4; r++)
                    op[(size_t)(row + r) * 1024] = f2bf((acc[mt][nt][r] + bi) * scv);
            }
        }
    } else {
#pragma unroll
        for (int nt = 0; nt < 4; nt++) {
            int n = col0 + wn + nt * 16 + l16;
            float bi = bias0[n];
#pragma unroll
            for (int mt = 0; mt < 4; mt++) {
                int row = row0 + wm + mt * 16 + quad * 4;
#pragma unroll
                for (int r = 0; r < 4; r++)
                    Cf[(size_t)(row + r) * 1024 + n] = acc[mt][nt][r] + bi;
            }
        }
    }
}

// ---------------- sparse flash attention -----------------------------------
// grid (32 qblocks, 16 heads), 256 threads. Per wave: 32 queries.
// S = Q K^T in C-layout [q][key]; O^T = V^T P^T accumulated in C-layout [hd][q].
__global__ __launch_bounds__(256) void attn_kernel(const uint16_t* __restrict__ Qg,
                                                   const uint16_t* __restrict__ Kg,
                                                   const uint16_t* __restrict__ Vg,
                                                   uint16_t* __restrict__ Og) {
    __shared__ __attribute__((aligned(16))) uint16_t Qs[128 * 64];
    __shared__ __attribute__((aligned(16))) uint16_t Ks[64 * 64];
    __shared__ __attribute__((aligned(16))) uint16_t Vts[64 * 64];  // [hd][key]
    __shared__ __attribute__((aligned(16))) uint16_t Ps[4][32 * 64];
    __shared__ float stats[4][32];

    const int b = blockIdx.x, h = blockIdx.y;
    const int tid = threadIdx.x;
    const int wave = tid >> 6, lane = tid & 63;
    const int quad = lane >> 4, l16 = lane & 15;

    // stage Q tile [128][64]
#pragma unroll
    for (int i = 0; i < 4; i++) {
        int u = wave * 4 + i;
        int row = u * 8 + (lane >> 3), c = lane & 7;
        gload_lds16(Qg + (size_t)(b * 128 + row) * 1024 + h * 64 + c * 8, Qs + u * 512);
    }

    float m_r[2][4], l_r[2][4];
    f32x4 o[4][2];
    const f32x4 z4 = {0.f, 0.f, 0.f, 0.f};
#pragma unroll
    for (int t = 0; t < 2; t++)
#pragma unroll
        for (int r = 0; r < 4; r++) { m_r[t][r] = -3e38f; l_r[t][r] = 0.f; }
#pragma unroll
    for (int mt = 0; mt < 4; mt++) { o[mt][0] = z4; o[mt][1] = z4; }

    const int nprev = 33 * b;
    const int ngc = (nprev + 63) >> 6;

    for (int ch = 0; ch < ngc + 2; ch++) {
        const bool own = (ch >= ngc);
        const int cb = ch - ngc;

        __syncthreads();
        // stage K chunk [64 keys][64 hd] via global_load_lds
#pragma unroll
        for (int i = 0; i < 2; i++) {
            int u = wave * 2 + i;
            int kl = u * 8 + (lane >> 3), c = lane & 7;
            int key;
            if (own) key = b * 128 + cb * 64 + kl;
            else { int t = ch * 64 + kl; int kb = t / 33; int rr = t - kb * 33;
                   key = kb * 128 + (rr == 0 ? 0 : 95 + rr); }
            gload_lds16(Kg + (size_t)key * 1024 + h * 64 + c * 8, Ks + u * 512);
        }
        // stage V transposed [64 hd][64 keys]
#pragma unroll
        for (int i = 0; i < 2; i++) {
            int uu = tid + 256 * i;
            int kl = uu & 63, c = uu >> 6;  // c in 0..7 (hd chunk)
            int key;
            if (own) key = b * 128 + cb * 64 + kl;
            else { int t = ch * 64 + kl; int kb = t / 33; int rr = t - kb * 33;
                   key = kb * 128 + (rr == 0 ? 0 : 95 + rr); }
            const uint16_t* g = Vg + (size_t)key * 1024 + h * 64 + c * 8;
            uint4 w = *(const uint4*)g;
            uint32_t ww[4] = {w.x, w.y, w.z, w.w};
#pragma unroll
            for (int j = 0; j < 4; j++) {
                Vts[(c * 8 + 2 * j)     * 64 + kl] = (uint16_t)(ww[j] & 0xffffu);
                Vts[(c * 8 + 2 * j + 1) * 64 + kl] = (uint16_t)(ww[j] >> 16);
            }
        }
        __syncthreads();

        // S = Q K^T : M=32 q (2 tiles), N=64 keys (4 tiles), K=64 hd (2 steps)
        f32x4 s[2][4];
#pragma unroll
        for (int t = 0; t < 2; t++)
#pragma unroll
            for (int nt = 0; nt < 4; nt++) s[t][nt] = z4;
#pragma unroll
        for (int kk = 0; kk < 2; kk++) {
            bf16x8 qa[2], kf[4];
#pragma unroll
            for (int t = 0; t < 2; t++)
                qa[t] = *(const bf16x8*)(Qs + (wave * 32 + t * 16 + l16) * 64 + kk * 32 + quad * 8);
#pragma unroll
            for (int nt = 0; nt < 4; nt++)
                kf[nt] = *(const bf16x8*)(Ks + (nt * 16 + l16) * 64 + kk * 32 + quad * 8);
#pragma unroll
            for (int t = 0; t < 2; t++)
#pragma unroll
                for (int nt = 0; nt < 4; nt++)
                    s[t][nt] = __builtin_amdgcn_mfma_f32_16x16x32_bf16(qa[t], kf[nt], s[t][nt], 0, 0, 0);
        }

        // masking
        if (own) {
#pragma unroll
            for (int nt = 0; nt < 4; nt++) {
                int keyl = cb * 64 + nt * 16 + l16;
#pragma unroll
                for (int t = 0; t < 2; t++)
#pragma unroll
                    for (int r = 0; r < 4; r++) {
                        int ql = wave * 32 + t * 16 + quad * 4 + r;
                        if (keyl > ql) s[t][nt][r] = -1e30f;
                    }
            }
        } else if (ch == ngc - 1) {
#pragma unroll
            for (int nt = 0; nt < 4; nt++) {
                int tg = ch * 64 + nt * 16 + l16;
                if (tg >= nprev) {
#pragma unroll
                    for (int t = 0; t < 2; t++)
#pragma unroll
                        for (int r = 0; r < 4; r++) s[t][nt][r] = -1e30f;
                }
            }
        }

        // online softmax per row (t,r); row stats shared across 16-lane groups
#pragma unroll
        for (int t = 0; t < 2; t++)
#pragma unroll
            for (int r = 0; r < 4; r++) {
                float mx = fmaxf(fmaxf(s[t][0][r], s[t][1][r]), fmaxf(s[t][2][r], s[t][3][r]));
#pragma unroll
                for (int off = 1; off < 16; off <<= 1) mx = fmaxf(mx, __shfl_xor(mx, off));
                float mn = fmaxf(m_r[t][r], mx);
                float a = __expf(m_r[t][r] - mn);
                m_r[t][r] = mn;
                float ps = 0.f;
#pragma unroll
                for (int nt = 0; nt < 4; nt++) {
                    float p = __expf(s[t][nt][r] - mn);
                    s[t][nt][r] = p;
                    ps += p;
                }
#pragma unroll
                for (int off = 1; off < 16; off <<= 1) ps += __shfl_xor(ps, off);
                l_r[t][r] = l_r[t][r] * a + ps;
                if (l16 == 0) stats[wave][t * 16 + quad * 4 + r] = a;
            }

        // P (bf16) to LDS in [q_local][key] layout
#pragma unroll
        for (int t = 0; t < 2; t++)
#pragma unroll
            for (int nt = 0; nt < 4; nt++)
#pragma unroll
                for (int r = 0; r < 4; r++)
                    Ps[wave][(t * 16 + quad * 4 + r) * 64 + nt * 16 + l16] = f2bf(s[t][nt][r]);
        __threadfence_block();  // wave-private LDS RAW ordering

        float a0 = stats[wave][l16];
        float a1 = stats[wave][16 + l16];
#pragma unroll
        for (int mt = 0; mt < 4; mt++)
#pragma unroll
            for (int r = 0; r < 4; r++) { o[mt][0][r] *= a0; o[mt][1][r] *= a1; }

        // O^T += V^T P^T : M=64 hd (4 tiles), N=32 q (2 tiles), K=64 keys (2 steps)
#pragma unroll
        for (int kk = 0; kk < 2; kk++) {
            bf16x8 va[4], pb[2];
#pragma unroll
            for (int mt = 0; mt < 4; mt++)
                va[mt] = *(const bf16x8*)(Vts + (mt * 16 + l16) * 64 + kk * 32 + quad * 8);
#pragma unroll
            for (int nt = 0; nt < 2; nt++)
                pb[nt] = *(const bf16x8*)(&Ps[wave][(nt * 16 + l16) * 64 + kk * 32 + quad * 8]);
#pragma unroll
            for (int mt = 0; mt < 4; mt++)
#pragma unroll
                for (int nt = 0; nt < 2; nt++)
                    o[mt][nt] = __builtin_amdgcn_mfma_f32_16x16x32_bf16(va[mt], pb[nt], o[mt][nt], 0, 0, 0);
        }
    }

    // finalize: divide by l, store ctx bf16 [s][h*64+hd]
    if (l16 == 0) {
#pragma unroll
        for (int t = 0; t < 2; t++)
#pragma unroll
            for (int r = 0; r < 4; r++) stats[wave][t * 16 + quad * 4 + r] = l_r[t][r];
    }
    __threadfence_block();
#pragma unroll
    for (int nt = 0; nt < 2; nt++) {
        float li = 1.0f / stats[wave][nt * 16 + l16];
        int q = b * 128 + wave * 32 + nt * 16 + l16;
#pragma unroll
        for (int mt = 0; mt < 4; mt++) {
            ushort4 pk;
            pk.x = f2bf(o[mt][nt][0] * li);
            pk.y = f2bf(o[mt][nt][1] * li);
            pk.z = f2bf(o[mt][nt][2] * li);
            pk.w = f2bf(o[mt][nt][3] * li);
            *(ushort4*)(Og + (size_t)q * 1024 + h * 64 + mt * 16 + quad * 4) = pk;
        }
    }
}

// ---------------------------------------------------------------------------
extern "C" void kernel_launch(void* const* d_in, const int* in_sizes, int n_in,
                              void* d_out, int out_size, void* d_ws, size_t ws_size,
                              hipStream_t stream) {
    const float* x  = (const float*)d_in[0];
    const float* Wq = (const float*)d_in[1];
    const float* bq = (const float*)d_in[2];
    const float* Wk = (const float*)d_in[3];
    const float* bk = (const float*)d_in[4];
    const float* Wv = (const float*)d_in[5];
    const float* bv = (const float*)d_in[6];
    const float* Wo = (const float*)d_in[7];
    const float* bo = (const float*)d_in[8];
    float* out = (float*)d_out;

    uint8_t* ws = (uint8_t*)d_ws;
    uint16_t* x_bf  = (uint16_t*)(ws);                       // 8 MiB
    uint16_t* wqkvt = (uint16_t*)(ws + (8u << 20));          // 6 MiB  [3072][1024]
    uint16_t* wot   = (uint16_t*)(ws + (14u << 20));         // 2 MiB  [1024][1024]
    uint16_t* q_bf  = (uint16_t*)(ws + (16u << 20));         // 8 MiB
    // k_bf = q_bf + S*1024, v_bf = q_bf + 2*S*1024 (contiguous via GEMM 'which')
    uint16_t* k_bf  = (uint16_t*)(ws + (24u << 20));
    uint16_t* v_bf  = (uint16_t*)(ws + (32u << 20));
    uint16_t* ctx   = (uint16_t*)(ws + (40u << 20));         // 8 MiB
    if (ws_size < (48u << 20)) return;

    cvt_x_kernel<<<4096, 256, 0, stream>>>(x, x_bf);
    tpose4<<<dim3(16, 16, 4), 256, 0, stream>>>(Wq, Wk, Wv, Wo, wqkvt, wot);
    gemm_bt<<<dim3(24, 32), 256, 0, stream>>>(x_bf, wqkvt, bq, bk, bv,
                                              q_bf, nullptr, 0);
    attn_kernel<<<dim3(32, 16), 256, 0, stream>>>(q_bf, k_bf, v_bf, ctx);
    gemm_bt<<<dim3(8, 32), 256, 0, stream>>>(ctx, wot, bo, nullptr, nullptr,
                                             nullptr, out, 1);
}

// Round 2
// 212.757 us; speedup vs baseline: 1.2540x; 1.2540x over previous
//
#include <hip/hip_runtime.h>
#include <stdint.h>

// ---------------------------------------------------------------------------
// SparseAttention: B=1 S=4096 D=1024 H=16 HD=64, BLOCK=128 C=32
// Pipeline: cvt_x -> tpose4 (W->bf16 [N][K]) -> gemm_bt(QKV) -> attn -> gemm_bt(out)
// ---------------------------------------------------------------------------

#define S_LEN 4096
#define DMODEL 1024

typedef __bf16 bf16x8 __attribute__((ext_vector_type(8)));
typedef float  f32x4  __attribute__((ext_vector_type(4)));

__device__ __forceinline__ uint16_t f2bf(float f) {
    uint32_t u = __builtin_bit_cast(uint32_t, f);
    u += 0x7fffu + ((u >> 16) & 1u);   // RNE
    return (uint16_t)(u >> 16);
}

__device__ __forceinline__ uint32_t pack2bf(float lo, float hi) {
    return (uint32_t)f2bf(lo) | ((uint32_t)f2bf(hi) << 16);
}

__device__ __forceinline__ void gload_lds16(const uint16_t* g, uint16_t* l) {
    __builtin_amdgcn_global_load_lds(
        (const __attribute__((address_space(1))) void*)g,
        (__attribute__((address_space(3))) void*)l, 16, 0, 0);
}

// gather-key mapping: chunk ch (64 keys), local key kl
__device__ __forceinline__ int key_of(int b, int ngc, int ch, int kl) {
    if (ch >= ngc) return b * 128 + (ch - ngc) * 64 + kl;   // own block
    int t = ch * 64 + kl;                                    // prev-block gather
    int kb = t / 33, rr = t - kb * 33;
    return kb * 128 + (rr == 0 ? 0 : 95 + rr);
}

// ---------------- x fp32 -> bf16 -------------------------------------------
__global__ __launch_bounds__(256) void cvt_x_kernel(const float* __restrict__ x,
                                                    uint16_t* __restrict__ xb) {
    int i = (blockIdx.x * 256 + threadIdx.x) * 4;
    const float4 v = *(const float4*)(x + i);
    ushort4 o;
    o.x = f2bf(v.x); o.y = f2bf(v.y); o.z = f2bf(v.z); o.w = f2bf(v.w);
    *(ushort4*)(xb + i) = o;
}

// ---------------- W [K=1024][N=1024] fp32 -> [N][K] bf16 -------------------
__global__ __launch_bounds__(256) void tpose4(const float* __restrict__ Wq,
                                              const float* __restrict__ Wk,
                                              const float* __restrict__ Wv,
                                              const float* __restrict__ Wo,
                                              uint16_t* __restrict__ wqkvt,
                                              uint16_t* __restrict__ wot) {
    __shared__ float tile[64][65];
    const int z = blockIdx.z;
    const float* src = (z == 0) ? Wq : (z == 1) ? Wk : (z == 2) ? Wv : Wo;
    uint16_t* dst = (z < 3) ? (wqkvt + (size_t)z * 1024 * 1024) : wot;
    const int ro = blockIdx.y * 64, co = blockIdx.x * 64;
    const int c = threadIdx.x & 63, r4 = threadIdx.x >> 6;
#pragma unroll
    for (int i = 0; i < 16; i++) {
        int r = i * 4 + r4;
        tile[r][c] = src[(size_t)(ro + r) * 1024 + co + c];
    }
    __syncthreads();
#pragma unroll
    for (int i = 0; i < 16; i++) {
        int cc = i * 4 + r4;
        dst[(size_t)(co + cc) * 1024 + ro + c] = f2bf(tile[c][cc]);
    }
}

// ---------------- GEMM: C[M][N] = A[M][1024] * Bt[N][1024]^T ---------------
__global__ __launch_bounds__(256) void gemm_bt(const uint16_t* __restrict__ A,
                                               const uint16_t* __restrict__ Bt,
                                               const float* __restrict__ bias0,
                                               const float* __restrict__ bias1,
                                               const float* __restrict__ bias2,
                                               uint16_t* __restrict__ Cb,
                                               float* __restrict__ Cf,
                                               const int mode) {
    __shared__ __attribute__((aligned(16))) uint16_t As[128 * 64];
    __shared__ __attribute__((aligned(16))) uint16_t Bs[128 * 64];
    const int tid = threadIdx.x;
    const int wave = tid >> 6, lane = tid & 63;
    const int quad = lane >> 4, l16 = lane & 15;
    const int row0 = blockIdx.y * 128, col0 = blockIdx.x * 128;
    const int wm = (wave >> 1) * 64, wn = (wave & 1) * 64;
    const int srow = lane >> 3, scol = lane & 7;

    f32x4 acc[4][4];
    const f32x4 z4 = {0.f, 0.f, 0.f, 0.f};
#pragma unroll
    for (int i = 0; i < 4; i++)
#pragma unroll
        for (int j = 0; j < 4; j++) acc[i][j] = z4;

    for (int k0 = 0; k0 < 1024; k0 += 64) {
        __syncthreads();
#pragma unroll
        for (int i = 0; i < 4; i++) {
            int u = wave * 4 + i;
            int row = u * 8 + srow;
            gload_lds16(A  + (size_t)(row0 + row) * 1024 + k0 + scol * 8, As + u * 512);
            gload_lds16(Bt + (size_t)(col0 + row) * 1024 + k0 + scol * 8, Bs + u * 512);
        }
        __syncthreads();
#pragma unroll
        for (int kk = 0; kk < 2; kk++) {
            bf16x8 af[4], bfr[4];
#pragma unroll
            for (int mt = 0; mt < 4; mt++)
                af[mt] = *(const bf16x8*)(As + (wm + mt * 16 + l16) * 64 + kk * 32 + quad * 8);
#pragma unroll
            for (int nt = 0; nt < 4; nt++)
                bfr[nt] = *(const bf16x8*)(Bs + (wn + nt * 16 + l16) * 64 + kk * 32 + quad * 8);
#pragma unroll
            for (int mt = 0; mt < 4; mt++)
#pragma unroll
                for (int nt = 0; nt < 4; nt++)
                    acc[mt][nt] = __builtin_amdgcn_mfma_f32_16x16x32_bf16(
                        af[mt], bfr[nt], acc[mt][nt], 0, 0, 0);
        }
    }

    if (mode == 0) {
#pragma unroll
        for (int nt = 0; nt < 4; nt++) {
            int n = col0 + wn + nt * 16 + l16;
            int which = n >> 10, c = n & 1023;
            const float* bp = (which == 0) ? bias0 : (which == 1 ? bias1 : bias2);
            float bi = bp[c];
            float scv = (which == 0) ? 0.125f : 1.0f;
            uint16_t* op = Cb + (size_t)which * S_LEN * 1024 + c;
#pragma unroll
            for (int mt = 0; mt < 4; mt++) {
                int row = row0 + wm + mt * 16 + quad * 4;
#pragma unroll
                for (int r = 0; r < 4; r++)
                    op[(size_t)(row + r) * 1024] = f2bf((acc[mt][nt][r] + bi) * scv);
            }
        }
    } else {
#pragma unroll
        for (int nt = 0; nt < 4; nt++) {
            int n = col0 + wn + nt * 16 + l16;
            float bi = bias0[n];
#pragma unroll
            for (int mt = 0; mt < 4; mt++) {
                int row = row0 + wm + mt * 16 + quad * 4;
#pragma unroll
                for (int r = 0; r < 4; r++)
                    Cf[(size_t)(row + r) * 1024 + n] = acc[mt][nt][r] + bi;
            }
        }
    }
}

// ---------------- sparse flash attention (v2, transposed) ------------------
// 512 threads = 8 waves; waves 0-3 = group A (even chunks), 4-7 = group B (odd).
// Each wave: 32 q (qt=2 tiles), full 64-key chunk. S^T = K.Q^T (C: col=q,row=key).
// P^T B-frags built in-register via quad shuffles; O^T = V^T.P^T.
// Groups merge (m,l,O) once at the end through LDS.
__global__ __launch_bounds__(512, 4) void attn_kernel(const uint16_t* __restrict__ Qg,
                                                      const uint16_t* __restrict__ Kg,
                                                      const uint16_t* __restrict__ Vg,
                                                      uint16_t* __restrict__ Og) {
    __shared__ __attribute__((aligned(16))) uint16_t SM[32768];  // 64 KiB
    uint16_t* Qs    = SM;                 // [128][64]           16 KiB
    uint16_t* Kbufs = SM + 8192;          // [buf2][grp2][64*64] 32 KiB
    uint16_t* Vbufs = SM + 24576;         // [grp2][64*64] (V^T [hd][key]) 16 KiB

    const int h = blockIdx.y;
    const int b = (h < 8) ? (int)blockIdx.x : (31 - (int)blockIdx.x);  // CU pairing swizzle
    const int tid = threadIdx.x;
    const int wave = tid >> 6, lane = tid & 63;
    const int quad = lane >> 4, l16 = lane & 15;
    const int grp = wave >> 2, wq = wave & 3;

    const int nprev = 33 * b;
    const int ngc = (nprev + 63) >> 6;
    const int ntot = ngc + 2;
    const int nit = (ntot + 1) >> 1;
    const size_t hoff = (size_t)h * 64;

    const int kRow = wave * 8 + (lane >> 3);
    const int kCol = (lane & 7) * 8;

    // ---- stage Q [128][64] (2 segments per thread)
#pragma unroll
    for (int i = 0; i < 2; i++) {
        int seg = i * 8 + wave;
        int row = seg * 8 + (lane >> 3);
        gload_lds16(Qg + (size_t)(b * 128 + row) * 1024 + hoff + kCol, Qs + seg * 512);
    }
    // ---- stage K chunks 0,1 into buf 0
#pragma unroll
    for (int g = 0; g < 2; g++) {
        if (g < ntot) {
            int key = key_of(b, ngc, g, kRow);
            gload_lds16(Kg + (size_t)key * 1024 + hoff + kCol,
                        Kbufs + g * 4096 + wave * 512);
        }
    }
    __syncthreads();

    float m_run[2], l_run[2];
    f32x4 o[4][2];
    const f32x4 z4 = {0.f, 0.f, 0.f, 0.f};
#pragma unroll
    for (int qt = 0; qt < 2; qt++) { m_run[qt] = -3e38f; l_run[qt] = 0.f; }
#pragma unroll
    for (int mt = 0; mt < 4; mt++) { o[mt][0] = z4; o[mt][1] = z4; }

    int cur = 0;
    for (int it = 0; it < nit; it++) {
        // (b) V loads for THIS iteration's two chunks (issued first so the
        //     later V^T-write waitcnt doesn't drain the K prefetch)
        uint4 vreg[2];
#pragma unroll
        for (int g = 0; g < 2; g++) {
            int ch = 2 * it + g;
            if (ch < ntot) {
                int key = key_of(b, ngc, ch, lane);
                vreg[g] = *(const uint4*)(Vg + (size_t)key * 1024 + hoff + wave * 8);
            }
        }
        // (a) async K prefetch for NEXT iteration into the other buffer
#pragma unroll
        for (int g = 0; g < 2; g++) {
            int ch = 2 * (it + 1) + g;
            if (ch < ntot) {
                int key = key_of(b, ngc, ch, kRow);
                gload_lds16(Kg + (size_t)key * 1024 + hoff + kCol,
                            Kbufs + (cur ^ 1) * 8192 + g * 4096 + wave * 512);
            }
        }

        // (c) S^T = K.Q^T + online softmax for my group's chunk
        const int myc = 2 * it + grp;
        const bool have = (myc < ntot);
        uint32_t pk[4][2][2];   // packed bf16 P, [kt][qt][pairhalf]
        float al[2] = {1.f, 1.f};
        if (have) {
            const uint16_t* Kc = Kbufs + cur * 8192 + grp * 4096;
            f32x4 s[4][2];
#pragma unroll
            for (int kt = 0; kt < 4; kt++) { s[kt][0] = z4; s[kt][1] = z4; }
#pragma unroll
            for (int kk = 0; kk < 2; kk++) {
                bf16x8 ka[4], qb[2];
#pragma unroll
                for (int kt = 0; kt < 4; kt++)
                    ka[kt] = *(const bf16x8*)(Kc + (kt * 16 + l16) * 64 + kk * 32 + quad * 8);
#pragma unroll
                for (int qt = 0; qt < 2; qt++)
                    qb[qt] = *(const bf16x8*)(Qs + (wq * 32 + qt * 16 + l16) * 64 + kk * 32 + quad * 8);
#pragma unroll
                for (int kt = 0; kt < 4; kt++)
#pragma unroll
                    for (int qt = 0; qt < 2; qt++)
                        s[kt][qt] = __builtin_amdgcn_mfma_f32_16x16x32_bf16(
                            ka[kt], qb[qt], s[kt][qt], 0, 0, 0);
            }
            // masking (C layout: col=q=l16, row=key=kt*16+quad*4+r)
            if (myc >= ngc) {
                int cb = myc - ngc;
#pragma unroll
                for (int kt = 0; kt < 4; kt++) {
                    int keyl = cb * 64 + kt * 16 + quad * 4;
#pragma unroll
                    for (int qt = 0; qt < 2; qt++) {
                        int ql = wq * 32 + qt * 16 + l16;
#pragma unroll
                        for (int r = 0; r < 4; r++)
                            if (keyl + r > ql) s[kt][qt][r] = -1e30f;
                    }
                }
            } else if (myc == ngc - 1) {
#pragma unroll
                for (int kt = 0; kt < 4; kt++) {
                    int tg = myc * 64 + kt * 16 + quad * 4;
#pragma unroll
                    for (int r = 0; r < 4; r++)
                        if (tg + r >= nprev) {
                            s[kt][0][r] = -1e30f;
                            s[kt][1][r] = -1e30f;
                        }
                }
            }
            // online softmax, per qt (reduction over key = regs + quads)
#pragma unroll
            for (int qt = 0; qt < 2; qt++) {
                float mx = -3e38f;
#pragma unroll
                for (int kt = 0; kt < 4; kt++)
#pragma unroll
                    for (int r = 0; r < 4; r++) mx = fmaxf(mx, s[kt][qt][r]);
                mx = fmaxf(mx, __shfl_xor(mx, 16));
                mx = fmaxf(mx, __shfl_xor(mx, 32));
                float mn = fmaxf(m_run[qt], mx);
                float sub = fmaxf(mn, -1e20f);   // guard fully-masked rows
                al[qt] = __expf(m_run[qt] - sub);
                m_run[qt] = mn;
                float ps = 0.f;
#pragma unroll
                for (int kt = 0; kt < 4; kt++) {
                    float p0 = __expf(s[kt][qt][0] - sub);
                    float p1 = __expf(s[kt][qt][1] - sub);
                    float p2 = __expf(s[kt][qt][2] - sub);
                    float p3 = __expf(s[kt][qt][3] - sub);
                    ps += (p0 + p1) + (p2 + p3);
                    pk[kt][qt][0] = pack2bf(p0, p1);
                    pk[kt][qt][1] = pack2bf(p2, p3);
                }
                ps += __shfl_xor(ps, 16);
                ps += __shfl_xor(ps, 32);
                l_run[qt] = l_run[qt] * al[qt] + ps;
            }
        }

        // (d) V^T writes for both chunks ([hd][key], 2-way-free banks)
#pragma unroll
        for (int g = 0; g < 2; g++) {
            int ch = 2 * it + g;
            if (ch < ntot) {
                uint16_t* Vd = Vbufs + g * 4096;
                uint32_t ww[4] = {vreg[g].x, vreg[g].y, vreg[g].z, vreg[g].w};
#pragma unroll
                for (int j = 0; j < 4; j++) {
                    Vd[(wave * 8 + 2 * j) * 64 + lane]     = (uint16_t)(ww[j] & 0xffffu);
                    Vd[(wave * 8 + 2 * j + 1) * 64 + lane] = (uint16_t)(ww[j] >> 16);
                }
            }
        }
        __syncthreads();   // (e) V^T ready (also drains K prefetch)

        // (f) O^T += V^T . P^T
        if (have) {
            const uint16_t* Vc = Vbufs + grp * 4096;
#pragma unroll
            for (int mt = 0; mt < 4; mt++)
#pragma unroll
                for (int qt = 0; qt < 2; qt++)
#pragma unroll
                    for (int r = 0; r < 4; r++) o[mt][qt][r] *= al[qt];
            const int srcA = l16 + 32 * (quad & 1);
            const bool hi = (quad >> 1) != 0;
#pragma unroll
            for (int kk = 0; kk < 2; kk++) {
                bf16x8 va[4];
#pragma unroll
                for (int mt = 0; mt < 4; mt++)
                    va[mt] = *(const bf16x8*)(Vc + (mt * 16 + l16) * 64 + kk * 32 + quad * 8);
#pragma unroll
                for (int qt = 0; qt < 2; qt++) {
                    uint32_t u0a = (uint32_t)__shfl((int)pk[2 * kk][qt][0], srcA);
                    uint32_t u0b = (uint32_t)__shfl((int)pk[2 * kk + 1][qt][0], srcA);
                    uint32_t u1a = (uint32_t)__shfl((int)pk[2 * kk][qt][1], srcA);
                    uint32_t u1b = (uint32_t)__shfl((int)pk[2 * kk + 1][qt][1], srcA);
                    uint32_t u2a = (uint32_t)__shfl((int)pk[2 * kk][qt][0], srcA + 16);
                    uint32_t u2b = (uint32_t)__shfl((int)pk[2 * kk + 1][qt][0], srcA + 16);
                    uint32_t u3a = (uint32_t)__shfl((int)pk[2 * kk][qt][1], srcA + 16);
                    uint32_t u3b = (uint32_t)__shfl((int)pk[2 * kk + 1][qt][1], srcA + 16);
                    uint4 fr;
                    fr.x = hi ? u0b : u0a;
                    fr.y = hi ? u1b : u1a;
                    fr.z = hi ? u2b : u2a;
                    fr.w = hi ? u3b : u3a;
                    bf16x8 pb = __builtin_bit_cast(bf16x8, fr);
#pragma unroll
                    for (int mt = 0; mt < 4; mt++)
                        o[mt][qt] = __builtin_amdgcn_mfma_f32_16x16x32_bf16(
                            va[mt], pb, o[mt][qt], 0, 0, 0);
                }
            }
        }
        __syncthreads();   // (g) PV reads done before next iter's V writes
        cur ^= 1;
    }

    // ---- merge groups via LDS (reuse K/V region) ----
    float* Obuf = (float*)(SM + 8192);        // [128][68] f32
    float* mB = Obuf + 128 * 68;
    float* lB = mB + 128;
    if (grp == 1) {
#pragma unroll
        for (int qt = 0; qt < 2; qt++) {
            int ql = wq * 32 + qt * 16 + l16;
            if (quad == 0) { mB[ql] = m_run[qt]; lB[ql] = l_run[qt]; }
#pragma unroll
            for (int mt = 0; mt < 4; mt++)
                *(f32x4*)(Obuf + ql * 68 + mt * 16 + quad * 4) = o[mt][qt];
        }
    }
    __syncthreads();
    if (grp == 0) {
#pragma unroll
        for (int qt = 0; qt < 2; qt++) {
            int ql = wq * 32 + qt * 16 + l16;
            float mb = mB[ql], lb = lB[ql];
            float ms = fmaxf(m_run[qt], mb);
            float fa = __expf(m_run[qt] - ms);
            float fb = __expf(mb - ms);
            float inv = 1.0f / (l_run[qt] * fa + lb * fb);
            int q = b * 128 + ql;
#pragma unroll
            for (int mt = 0; mt < 4; mt++) {
                f32x4 ob = *(const f32x4*)(Obuf + ql * 68 + mt * 16 + quad * 4);
                ushort4 pko;
                pko.x = f2bf((o[mt][qt][0] * fa + ob[0] * fb) * inv);
                pko.y = f2bf((o[mt][qt][1] * fa + ob[1] * fb) * inv);
                pko.z = f2bf((o[mt][qt][2] * fa + ob[2] * fb) * inv);
                pko.w = f2bf((o[mt][qt][3] * fa + ob[3] * fb) * inv);
                *(ushort4*)(Og + (size_t)q * 1024 + hoff + mt * 16 + quad * 4) = pko;
            }
        }
    }
}

// ---------------------------------------------------------------------------
extern "C" void kernel_launch(void* const* d_in, const int* in_sizes, int n_in,
                              void* d_out, int out_size, void* d_ws, size_t ws_size,
                              hipStream_t stream) {
    const float* x  = (const float*)d_in[0];
    const float* Wq = (const float*)d_in[1];
    const float* bq = (const float*)d_in[2];
    const float* Wk = (const float*)d_in[3];
    const float* bk = (const float*)d_in[4];
    const float* Wv = (const float*)d_in[5];
    const float* bv = (const float*)d_in[6];
    const float* Wo = (const float*)d_in[7];
    const float* bo = (const float*)d_in[8];
    float* out = (float*)d_out;

    uint8_t* ws = (uint8_t*)d_ws;
    uint16_t* x_bf  = (uint16_t*)(ws);                       // 8 MiB
    uint16_t* wqkvt = (uint16_t*)(ws + (8u << 20));          // 6 MiB  [3072][1024]
    uint16_t* wot   = (uint16_t*)(ws + (14u << 20));         // 2 MiB  [1024][1024]
    uint16_t* q_bf  = (uint16_t*)(ws + (16u << 20));         // 8 MiB
    uint16_t* k_bf  = (uint16_t*)(ws + (24u << 20));
    uint16_t* v_bf  = (uint16_t*)(ws + (32u << 20));
    uint16_t* ctx   = (uint16_t*)(ws + (40u << 20));         // 8 MiB
    if (ws_size < (48u << 20)) return;

    cvt_x_kernel<<<4096, 256, 0, stream>>>(x, x_bf);
    tpose4<<<dim3(16, 16, 4), 256, 0, stream>>>(Wq, Wk, Wv, Wo, wqkvt, wot);
    gemm_bt<<<dim3(24, 32), 256, 0, stream>>>(x_bf, wqkvt, bq, bk, bv,
                                              q_bf, nullptr, 0);
    attn_kernel<<<dim3(32, 16), 512, 0, stream>>>(q_bf, k_bf, v_bf, ctx);
    gemm_bt<<<dim3(8, 32), 256, 0, stream>>>(ctx, wot, bo, nullptr, nullptr,
                                             nullptr, out, 1);
}

// Round 3
// 196.901 us; speedup vs baseline: 1.3550x; 1.0805x over previous
//
#include <hip/hip_runtime.h>
#include <stdint.h>

// ---------------------------------------------------------------------------
// SparseAttention: B=1 S=4096 D=1024 H=16 HD=64, BLOCK=128 C=32
// Pipeline: cvt_x -> tpose4 (W->bf16 [N][K]) -> gemm_bt(QKV) -> attn -> gemm_bt(out)
// LDS tiles are XOR-swizzled (granule = chunk ^ (row&7)) to kill the 128B-row-
// stride bank conflicts; swizzle is applied on the *global source column* so
// global_load_lds's lane-contiguous LDS destination is preserved.
// ---------------------------------------------------------------------------

#define S_LEN 4096
#define DMODEL 1024

typedef __bf16 bf16x8 __attribute__((ext_vector_type(8)));
typedef float  f32x4  __attribute__((ext_vector_type(4)));

__device__ __forceinline__ uint16_t f2bf(float f) {
    uint32_t u = __builtin_bit_cast(uint32_t, f);
    u += 0x7fffu + ((u >> 16) & 1u);   // RNE
    return (uint16_t)(u >> 16);
}

__device__ __forceinline__ uint32_t pack2bf(float lo, float hi) {
    return (uint32_t)f2bf(lo) | ((uint32_t)f2bf(hi) << 16);
}

__device__ __forceinline__ void gload_lds16(const uint16_t* g, uint16_t* l) {
    __builtin_amdgcn_global_load_lds(
        (const __attribute__((address_space(1))) void*)g,
        (__attribute__((address_space(3))) void*)l, 16, 0, 0);
}

// gather-key mapping: chunk ch (64 keys), local key kl
__device__ __forceinline__ int key_of(int b, int ngc, int ch, int kl) {
    if (ch >= ngc) return b * 128 + (ch - ngc) * 64 + kl;   // own block
    int t = ch * 64 + kl;                                    // prev-block gather
    int kb = t / 33, rr = t - kb * 33;
    return kb * 128 + (rr == 0 ? 0 : 95 + rr);
}

// ---------------- x fp32 -> bf16 -------------------------------------------
__global__ __launch_bounds__(256) void cvt_x_kernel(const float* __restrict__ x,
                                                    uint16_t* __restrict__ xb) {
    int i = (blockIdx.x * 256 + threadIdx.x) * 4;
    const float4 v = *(const float4*)(x + i);
    ushort4 o;
    o.x = f2bf(v.x); o.y = f2bf(v.y); o.z = f2bf(v.z); o.w = f2bf(v.w);
    *(ushort4*)(xb + i) = o;
}

// ---------------- W [K=1024][N=1024] fp32 -> [N][K] bf16 -------------------
__global__ __launch_bounds__(256) void tpose4(const float* __restrict__ Wq,
                                              const float* __restrict__ Wk,
                                              const float* __restrict__ Wv,
                                              const float* __restrict__ Wo,
                                              uint16_t* __restrict__ wqkvt,
                                              uint16_t* __restrict__ wot) {
    __shared__ float tile[64][65];
    const int z = blockIdx.z;
    const float* src = (z == 0) ? Wq : (z == 1) ? Wk : (z == 2) ? Wv : Wo;
    uint16_t* dst = (z < 3) ? (wqkvt + (size_t)z * 1024 * 1024) : wot;
    const int ro = blockIdx.y * 64, co = blockIdx.x * 64;
    const int c = threadIdx.x & 63, r4 = threadIdx.x >> 6;
#pragma unroll
    for (int i = 0; i < 16; i++) {
        int r = i * 4 + r4;
        tile[r][c] = src[(size_t)(ro + r) * 1024 + co + c];
    }
    __syncthreads();
#pragma unroll
    for (int i = 0; i < 16; i++) {
        int cc = i * 4 + r4;
        dst[(size_t)(co + cc) * 1024 + ro + c] = f2bf(tile[c][cc]);
    }
}

// ---------------- GEMM: C[M][N] = A[M][1024] * Bt[N][1024]^T ---------------
// MODE 0: N=3072 qkv -> bf16, bias + q*0.125, operand-swapped MFMA so each
//         thread stores 4 consecutive n (ushort4, 32B-coalesced segments).
// MODE 1: N=1024 -> fp32 + bias, coalesced dword stores.
template <int MODE>
__global__ __launch_bounds__(256) void gemm_bt(const uint16_t* __restrict__ A,
                                               const uint16_t* __restrict__ Bt,
                                               const float* __restrict__ bias0,
                                               const float* __restrict__ bias1,
                                               const float* __restrict__ bias2,
                                               uint16_t* __restrict__ Cb,
                                               float* __restrict__ Cf) {
    __shared__ __attribute__((aligned(16))) uint16_t As[128 * 64];
    __shared__ __attribute__((aligned(16))) uint16_t Bs[128 * 64];
    const int tid = threadIdx.x;
    const int wave = tid >> 6, lane = tid & 63;
    const int quad = lane >> 4, l16 = lane & 15;
    const int row0 = blockIdx.y * 128, col0 = blockIdx.x * 128;
    const int wm = (wave >> 1) * 64, wn = (wave & 1) * 64;
    const int srow = lane >> 3, scol = lane & 7;
    const int gcol = (scol ^ srow) * 8;       // swizzled source column chunk
    const int sw = (l16 & 7);                 // fragment-read swizzle key

    f32x4 acc[4][4];
    const f32x4 z4 = {0.f, 0.f, 0.f, 0.f};
#pragma unroll
    for (int i = 0; i < 4; i++)
#pragma unroll
        for (int j = 0; j < 4; j++) acc[i][j] = z4;

    for (int k0 = 0; k0 < 1024; k0 += 64) {
        __syncthreads();
#pragma unroll
        for (int i = 0; i < 4; i++) {
            int u = wave * 4 + i;
            int row = u * 8 + srow;
            gload_lds16(A  + (size_t)(row0 + row) * 1024 + k0 + gcol, As + u * 512);
            gload_lds16(Bt + (size_t)(col0 + row) * 1024 + k0 + gcol, Bs + u * 512);
        }
        __syncthreads();
#pragma unroll
        for (int kk = 0; kk < 2; kk++) {
            bf16x8 af[4], bfr[4];
#pragma unroll
            for (int mt = 0; mt < 4; mt++)
                af[mt] = *(const bf16x8*)(As + (wm + mt * 16 + l16) * 64 + ((kk * 4 + quad) ^ sw) * 8);
#pragma unroll
            for (int nt = 0; nt < 4; nt++)
                bfr[nt] = *(const bf16x8*)(Bs + (wn + nt * 16 + l16) * 64 + ((kk * 4 + quad) ^ sw) * 8);
#pragma unroll
            for (int mt = 0; mt < 4; mt++)
#pragma unroll
                for (int nt = 0; nt < 4; nt++) {
                    if (MODE == 0)   // C^T orientation: reg index = n
                        acc[mt][nt] = __builtin_amdgcn_mfma_f32_16x16x32_bf16(
                            bfr[nt], af[mt], acc[mt][nt], 0, 0, 0);
                    else
                        acc[mt][nt] = __builtin_amdgcn_mfma_f32_16x16x32_bf16(
                            af[mt], bfr[nt], acc[mt][nt], 0, 0, 0);
                }
        }
    }

    if (MODE == 0) {
        // acc[mt][nt]: row s = row0+wm+mt*16+l16, cols n = col0+wn+nt*16+quad*4+r
#pragma unroll
        for (int nt = 0; nt < 4; nt++) {
            int n = col0 + wn + nt * 16 + quad * 4;
            int which = n >> 10, c = n & 1023;
            const float* bp = (which == 0) ? bias0 : (which == 1 ? bias1 : bias2);
            const float4 b4 = *(const float4*)(bp + c);
            float scv = (which == 0) ? 0.125f : 1.0f;
            uint16_t* op = Cb + (size_t)which * S_LEN * 1024 + c;
#pragma unroll
            for (int mt = 0; mt < 4; mt++) {
                int s = row0 + wm + mt * 16 + l16;
                ushort4 pkv;
                pkv.x = f2bf((acc[mt][nt][0] + b4.x) * scv);
                pkv.y = f2bf((acc[mt][nt][1] + b4.y) * scv);
                pkv.z = f2bf((acc[mt][nt][2] + b4.z) * scv);
                pkv.w = f2bf((acc[mt][nt][3] + b4.w) * scv);
                *(ushort4*)(op + (size_t)s * 1024) = pkv;
            }
        }
    } else {
#pragma unroll
        for (int nt = 0; nt < 4; nt++) {
            int n = col0 + wn + nt * 16 + l16;
            float bi = bias0[n];
#pragma unroll
            for (int mt = 0; mt < 4; mt++) {
                int row = row0 + wm + mt * 16 + quad * 4;
#pragma unroll
                for (int r = 0; r < 4; r++)
                    Cf[(size_t)(row + r) * 1024 + n] = acc[mt][nt][r] + bi;
            }
        }
    }
}

// ---------------- sparse flash attention (v2, transposed) ------------------
// 512 threads = 8 waves; waves 0-3 = group A (even chunks), 4-7 = group B (odd).
// Each wave: 32 q (qt=2 tiles), full 64-key chunk. S^T = K.Q^T (C: col=q,row=key).
// P^T B-frags built in-register via quad shuffles; O^T = V^T.P^T.
// Groups merge (m,l,O) once at the end through LDS.
__global__ __launch_bounds__(512, 4) void attn_kernel(const uint16_t* __restrict__ Qg,
                                                      const uint16_t* __restrict__ Kg,
                                                      const uint16_t* __restrict__ Vg,
                                                      uint16_t* __restrict__ Og) {
    __shared__ __attribute__((aligned(16))) uint16_t SM[32768];  // 64 KiB
    uint16_t* Qs    = SM;                 // [128][64]           16 KiB
    uint16_t* Kbufs = SM + 8192;          // [buf2][grp2][64*64] 32 KiB
    uint16_t* Vbufs = SM + 24576;         // [grp2][64*64] (V^T [hd][key]) 16 KiB

    const int h = blockIdx.y;
    const int b = (h < 8) ? (int)blockIdx.x : (31 - (int)blockIdx.x);  // CU pairing swizzle
    const int tid = threadIdx.x;
    const int wave = tid >> 6, lane = tid & 63;
    const int quad = lane >> 4, l16 = lane & 15;
    const int grp = wave >> 2, wq = wave & 3;
    const int sw = (l16 & 7);

    const int nprev = 33 * b;
    const int ngc = (nprev + 63) >> 6;
    const int ntot = ngc + 2;
    const int nit = (ntot + 1) >> 1;
    const size_t hoff = (size_t)h * 64;

    const int kRow = wave * 8 + (lane >> 3);
    const int gCol = ((lane & 7) ^ (lane >> 3)) * 8;   // swizzled source chunk

    // ---- stage Q [128][64] (2 segments per thread)
#pragma unroll
    for (int i = 0; i < 2; i++) {
        int seg = i * 8 + wave;
        int row = seg * 8 + (lane >> 3);
        gload_lds16(Qg + (size_t)(b * 128 + row) * 1024 + hoff + gCol, Qs + seg * 512);
    }
    // ---- stage K chunks 0,1 into buf 0
#pragma unroll
    for (int g = 0; g < 2; g++) {
        if (g < ntot) {
            int key = key_of(b, ngc, g, kRow);
            gload_lds16(Kg + (size_t)key * 1024 + hoff + gCol,
                        Kbufs + g * 4096 + wave * 512);
        }
    }
    __syncthreads();

    float m_run[2], l_run[2];
    f32x4 o[4][2];
    const f32x4 z4 = {0.f, 0.f, 0.f, 0.f};
#pragma unroll
    for (int qt = 0; qt < 2; qt++) { m_run[qt] = -3e38f; l_run[qt] = 0.f; }
#pragma unroll
    for (int mt = 0; mt < 4; mt++) { o[mt][0] = z4; o[mt][1] = z4; }

    int cur = 0;
    for (int it = 0; it < nit; it++) {
        // (b) V loads for THIS iteration's two chunks
        uint4 vreg[2];
#pragma unroll
        for (int g = 0; g < 2; g++) {
            int ch = 2 * it + g;
            if (ch < ntot) {
                int key = key_of(b, ngc, ch, lane);
                vreg[g] = *(const uint4*)(Vg + (size_t)key * 1024 + hoff + wave * 8);
            }
        }
        // (a) async K prefetch for NEXT iteration into the other buffer
#pragma unroll
        for (int g = 0; g < 2; g++) {
            int ch = 2 * (it + 1) + g;
            if (ch < ntot) {
                int key = key_of(b, ngc, ch, kRow);
                gload_lds16(Kg + (size_t)key * 1024 + hoff + gCol,
                            Kbufs + (cur ^ 1) * 8192 + g * 4096 + wave * 512);
            }
        }

        // (c) S^T = K.Q^T + online softmax for my group's chunk
        const int myc = 2 * it + grp;
        const bool have = (myc < ntot);
        uint32_t pk[4][2][2];   // packed bf16 P, [kt][qt][pairhalf]
        float al[2] = {1.f, 1.f};
        if (have) {
            const uint16_t* Kc = Kbufs + cur * 8192 + grp * 4096;
            f32x4 s[4][2];
#pragma unroll
            for (int kt = 0; kt < 4; kt++) { s[kt][0] = z4; s[kt][1] = z4; }
#pragma unroll
            for (int kk = 0; kk < 2; kk++) {
                bf16x8 ka[4], qb[2];
#pragma unroll
                for (int kt = 0; kt < 4; kt++)
                    ka[kt] = *(const bf16x8*)(Kc + (kt * 16 + l16) * 64 + ((kk * 4 + quad) ^ sw) * 8);
#pragma unroll
                for (int qt = 0; qt < 2; qt++)
                    qb[qt] = *(const bf16x8*)(Qs + (wq * 32 + qt * 16 + l16) * 64 + ((kk * 4 + quad) ^ sw) * 8);
#pragma unroll
                for (int kt = 0; kt < 4; kt++)
#pragma unroll
                    for (int qt = 0; qt < 2; qt++)
                        s[kt][qt] = __builtin_amdgcn_mfma_f32_16x16x32_bf16(
                            ka[kt], qb[qt], s[kt][qt], 0, 0, 0);
            }
            // masking (C layout: col=q=l16, row=key=kt*16+quad*4+r)
            if (myc >= ngc) {
                int cb = myc - ngc;
#pragma unroll
                for (int kt = 0; kt < 4; kt++) {
                    int keyl = cb * 64 + kt * 16 + quad * 4;
#pragma unroll
                    for (int qt = 0; qt < 2; qt++) {
                        int ql = wq * 32 + qt * 16 + l16;
#pragma unroll
                        for (int r = 0; r < 4; r++)
                            if (keyl + r > ql) s[kt][qt][r] = -1e30f;
                    }
                }
            } else if (myc == ngc - 1) {
#pragma unroll
                for (int kt = 0; kt < 4; kt++) {
                    int tg = myc * 64 + kt * 16 + quad * 4;
#pragma unroll
                    for (int r = 0; r < 4; r++)
                        if (tg + r >= nprev) {
                            s[kt][0][r] = -1e30f;
                            s[kt][1][r] = -1e30f;
                        }
                }
            }
            // online softmax, per qt (reduction over key = regs + quads)
#pragma unroll
            for (int qt = 0; qt < 2; qt++) {
                float mx = -3e38f;
#pragma unroll
                for (int kt = 0; kt < 4; kt++)
#pragma unroll
                    for (int r = 0; r < 4; r++) mx = fmaxf(mx, s[kt][qt][r]);
                mx = fmaxf(mx, __shfl_xor(mx, 16));
                mx = fmaxf(mx, __shfl_xor(mx, 32));
                float mn = fmaxf(m_run[qt], mx);
                float sub = fmaxf(mn, -1e20f);   // guard fully-masked rows
                al[qt] = __expf(m_run[qt] - sub);
                m_run[qt] = mn;
                float ps = 0.f;
#pragma unroll
                for (int kt = 0; kt < 4; kt++) {
                    float p0 = __expf(s[kt][qt][0] - sub);
                    float p1 = __expf(s[kt][qt][1] - sub);
                    float p2 = __expf(s[kt][qt][2] - sub);
                    float p3 = __expf(s[kt][qt][3] - sub);
                    ps += (p0 + p1) + (p2 + p3);
                    pk[kt][qt][0] = pack2bf(p0, p1);
                    pk[kt][qt][1] = pack2bf(p2, p3);
                }
                ps += __shfl_xor(ps, 16);
                ps += __shfl_xor(ps, 32);
                l_run[qt] = l_run[qt] * al[qt] + ps;
            }
        }

        // (d) V^T writes for both chunks ([hd][key], key-chunk granules swizzled)
#pragma unroll
        for (int g = 0; g < 2; g++) {
            int ch = 2 * it + g;
            if (ch < ntot) {
                uint16_t* Vd = Vbufs + g * 4096;
                uint32_t ww[4] = {vreg[g].x, vreg[g].y, vreg[g].z, vreg[g].w};
                const int kc = (lane >> 3), kin = (lane & 7);
#pragma unroll
                for (int j = 0; j < 4; j++) {
                    int hd0 = wave * 8 + 2 * j, hd1 = hd0 + 1;
                    Vd[hd0 * 64 + ((kc ^ (hd0 & 7)) * 8 + kin)] = (uint16_t)(ww[j] & 0xffffu);
                    Vd[hd1 * 64 + ((kc ^ (hd1 & 7)) * 8 + kin)] = (uint16_t)(ww[j] >> 16);
                }
            }
        }
        __syncthreads();   // (e) V^T ready (also drains K prefetch)

        // (f) O^T += V^T . P^T
        if (have) {
            const uint16_t* Vc = Vbufs + grp * 4096;
#pragma unroll
            for (int mt = 0; mt < 4; mt++)
#pragma unroll
                for (int qt = 0; qt < 2; qt++)
#pragma unroll
                    for (int r = 0; r < 4; r++) o[mt][qt][r] *= al[qt];
            const int srcA = l16 + 32 * (quad & 1);
            const bool hi = (quad >> 1) != 0;
#pragma unroll
            for (int kk = 0; kk < 2; kk++) {
                bf16x8 va[4];
#pragma unroll
                for (int mt = 0; mt < 4; mt++)
                    va[mt] = *(const bf16x8*)(Vc + (mt * 16 + l16) * 64 + ((kk * 4 + quad) ^ sw) * 8);
#pragma unroll
                for (int qt = 0; qt < 2; qt++) {
                    uint32_t u0a = (uint32_t)__shfl((int)pk[2 * kk][qt][0], srcA);
                    uint32_t u0b = (uint32_t)__shfl((int)pk[2 * kk + 1][qt][0], srcA);
                    uint32_t u1a = (uint32_t)__shfl((int)pk[2 * kk][qt][1], srcA);
                    uint32_t u1b = (uint32_t)__shfl((int)pk[2 * kk + 1][qt][1], srcA);
                    uint32_t u2a = (uint32_t)__shfl((int)pk[2 * kk][qt][0], srcA + 16);
                    uint32_t u2b = (uint32_t)__shfl((int)pk[2 * kk + 1][qt][0], srcA + 16);
                    uint32_t u3a = (uint32_t)__shfl((int)pk[2 * kk][qt][1], srcA + 16);
                    uint32_t u3b = (uint32_t)__shfl((int)pk[2 * kk + 1][qt][1], srcA + 16);
                    uint4 fr;
                    fr.x = hi ? u0b : u0a;
                    fr.y = hi ? u1b : u1a;
                    fr.z = hi ? u2b : u2a;
                    fr.w = hi ? u3b : u3a;
                    bf16x8 pb = __builtin_bit_cast(bf16x8, fr);
#pragma unroll
                    for (int mt = 0; mt < 4; mt++)
                        o[mt][qt] = __builtin_amdgcn_mfma_f32_16x16x32_bf16(
                            va[mt], pb, o[mt][qt], 0, 0, 0);
                }
            }
        }
        __syncthreads();   // (g) PV reads done before next iter's V writes
        cur ^= 1;
    }

    // ---- merge groups via LDS (reuse K/V region) ----
    float* Obuf = (float*)(SM + 8192);        // [128][68] f32
    float* mB = Obuf + 128 * 68;
    float* lB = mB + 128;
    if (grp == 1) {
#pragma unroll
        for (int qt = 0; qt < 2; qt++) {
            int ql = wq * 32 + qt * 16 + l16;
            if (quad == 0) { mB[ql] = m_run[qt]; lB[ql] = l_run[qt]; }
#pragma unroll
            for (int mt = 0; mt < 4; mt++)
                *(f32x4*)(Obuf + ql * 68 + mt * 16 + quad * 4) = o[mt][qt];
        }
    }
    __syncthreads();
    if (grp == 0) {
#pragma unroll
        for (int qt = 0; qt < 2; qt++) {
            int ql = wq * 32 + qt * 16 + l16;
            float mb = mB[ql], lb = lB[ql];
            float ms = fmaxf(m_run[qt], mb);
            float fa = __expf(m_run[qt] - ms);
            float fb = __expf(mb - ms);
            float inv = 1.0f / (l_run[qt] * fa + lb * fb);
            int q = b * 128 + ql;
#pragma unroll
            for (int mt = 0; mt < 4; mt++) {
                f32x4 ob = *(const f32x4*)(Obuf + ql * 68 + mt * 16 + quad * 4);
                ushort4 pko;
                pko.x = f2bf((o[mt][qt][0] * fa + ob[0] * fb) * inv);
                pko.y = f2bf((o[mt][qt][1] * fa + ob[1] * fb) * inv);
                pko.z = f2bf((o[mt][qt][2] * fa + ob[2] * fb) * inv);
                pko.w = f2bf((o[mt][qt][3] * fa + ob[3] * fb) * inv);
                *(ushort4*)(Og + (size_t)q * 1024 + hoff + mt * 16 + quad * 4) = pko;
            }
        }
    }
}

// ---------------------------------------------------------------------------
extern "C" void kernel_launch(void* const* d_in, const int* in_sizes, int n_in,
                              void* d_out, int out_size, void* d_ws, size_t ws_size,
                              hipStream_t stream) {
    const float* x  = (const float*)d_in[0];
    const float* Wq = (const float*)d_in[1];
    const float* bq = (const float*)d_in[2];
    const float* Wk = (const float*)d_in[3];
    const float* bk = (const float*)d_in[4];
    const float* Wv = (const float*)d_in[5];
    const float* bv = (const float*)d_in[6];
    const float* Wo = (const float*)d_in[7];
    const float* bo = (const float*)d_in[8];
    float* out = (float*)d_out;

    uint8_t* ws = (uint8_t*)d_ws;
    uint16_t* x_bf  = (uint16_t*)(ws);                       // 8 MiB
    uint16_t* wqkvt = (uint16_t*)(ws + (8u << 20));          // 6 MiB  [3072][1024]
    uint16_t* wot   = (uint16_t*)(ws + (14u << 20));         // 2 MiB  [1024][1024]
    uint16_t* q_bf  = (uint16_t*)(ws + (16u << 20));         // 8 MiB
    uint16_t* k_bf  = (uint16_t*)(ws + (24u << 20));
    uint16_t* v_bf  = (uint16_t*)(ws + (32u << 20));
    uint16_t* ctx   = (uint16_t*)(ws + (40u << 20));         // 8 MiB
    if (ws_size < (48u << 20)) return;

    cvt_x_kernel<<<4096, 256, 0, stream>>>(x, x_bf);
    tpose4<<<dim3(16, 16, 4), 256, 0, stream>>>(Wq, Wk, Wv, Wo, wqkvt, wot);
    gemm_bt<0><<<dim3(24, 32), 256, 0, stream>>>(x_bf, wqkvt, bq, bk, bv,
                                                 q_bf, nullptr);
    attn_kernel<<<dim3(32, 16), 512, 0, stream>>>(q_bf, k_bf, v_bf, ctx);
    gemm_bt<1><<<dim3(8, 32), 256, 0, stream>>>(ctx, wot, bo, nullptr, nullptr,
                                                nullptr, out);
}